// Round 5
// baseline (86.558 us; speedup 1.0000x reference)
//
#include <hip/hip_runtime.h>
#include <hip/hip_bf16.h>

#define GD     50          // grid cells per dim
#define NC     (GD*GD*GD)  // 125000
#define GORG   5.0f
#define GINV   5.0f        // 1/cellsize
#define CAPK   256         // in-radius candidate capacity per centroid
#define SPCAP  2048        // scanned-candidate capacity per centroid
#define RADIUS_F 0.2f
#define R2SAFE 0.0401f

typedef unsigned long long ull;
typedef __attribute__((ext_vector_type(4))) _Float16 f16x4;
typedef __attribute__((ext_vector_type(8))) _Float16 f16x8;
typedef __attribute__((ext_vector_type(4))) float    f32x4;

__device__ __forceinline__ int cellcoord(float v) {
    int c = (int)floorf((v + GORG) * GINV);
    return min(max(c, 0), GD - 1);
}

// -------- K1: pack pt4, cell ids, cell counts, f16 weights ----------------
__global__ void sa_prep_kernel(const float* __restrict__ vtx,
                               float4* __restrict__ pt4,
                               int* __restrict__ cid,
                               int* __restrict__ cellCnt,
                               int N,
                               const float* __restrict__ W1,
                               const float* __restrict__ W2,
                               const float* __restrict__ W3,
                               _Float16* __restrict__ wf16) {
    int i = blockIdx.x * blockDim.x + threadIdx.x;
    int stride = gridDim.x * blockDim.x;
    for (int p = i; p < N; p += stride) {
        float x = vtx[3 * p], y = vtx[3 * p + 1], z = vtx[3 * p + 2];
        float sn = fmaf(z, z, fmaf(y, y, x * x));
        pt4[p] = make_float4(x, y, z, sn);
        int cc = (cellcoord(z) * GD + cellcoord(y)) * GD + cellcoord(x);
        cid[p] = cc;
        atomicAdd(&cellCnt[cc], 1);
    }
    // W1t: [64 col][16 k], k>=6 zero (offset 0)
    for (int e = i; e < 1024; e += stride) {
        int col = e >> 4, k = e & 15;
        wf16[e] = (k < 6) ? (_Float16)W1[k * 64 + col] : (_Float16)0.f;
    }
    // W2t: [64 col][64 k] (offset 1024)
    for (int e = i; e < 4096; e += stride) {
        int col = e >> 6, k = e & 63;
        wf16[1024 + e] = (_Float16)W2[k * 64 + col];
    }
    // W3t: [128 col][64 k] (offset 5120)
    for (int e = i; e < 8192; e += stride) {
        int col = e >> 6, k = e & 63;
        wf16[5120 + e] = (_Float16)W3[k * 128 + col];
    }
}

// -------- K2: CSR offsets via block scan + one atomic base per block ------
__global__ __launch_bounds__(256) void sa_offsets_kernel(
    const int* __restrict__ cellCnt, int* __restrict__ cellStart,
    int* __restrict__ cellCur, int* __restrict__ cursor) {
    __shared__ int sc[256];
    __shared__ int base_s;
    int t = threadIdx.x;
    int i = blockIdx.x * 256 + t;
    int c = (i < NC) ? cellCnt[i] : 0;
    sc[t] = c;
    __syncthreads();
    for (int d = 1; d < 256; d <<= 1) {
        int o = (t >= d) ? sc[t - d] : 0;
        __syncthreads();
        sc[t] += o;
        __syncthreads();
    }
    if (t == 255) base_s = atomicAdd(cursor, sc[255]);
    __syncthreads();
    int start = base_s + sc[t] - c;
    if (i < NC) { cellStart[i] = start; cellCur[i] = start; }
}

// -------- K3: scatter points into cell-sorted order -----------------------
__global__ void sa_scatter_kernel(const float4* __restrict__ pt4,
                                  const int* __restrict__ cid,
                                  int* __restrict__ cellCur,
                                  float4* __restrict__ sorted4,
                                  int* __restrict__ sidx, int N) {
    int p = blockIdx.x * blockDim.x + threadIdx.x;
    if (p < N) {
        int pos = atomicAdd(&cellCur[cid[p]], 1);
        sorted4[pos] = pt4[p];
        sidx[pos] = p;
    }
}

// -------- K4: collect in-radius candidates + top-64 select ----------------
__global__ __launch_bounds__(256) void sa_collect_kernel(
    const float4* __restrict__ pt4, const int* __restrict__ cidx,
    const float4* __restrict__ sorted4, const int* __restrict__ sidx,
    const int* __restrict__ cellCnt, const int* __restrict__ cellStart,
    int* __restrict__ selG, int* __restrict__ nselG) {

    __shared__ int spbuf[4][SPCAP];      // 32 KB
    __shared__ ull  keys[4][CAPK];       // 8 KB
    __shared__ int  selb[4][64];
    __shared__ int  scnt_s[4];

    int t = threadIdx.x, w = t >> 6, lane = t & 63;
    int c = blockIdx.x * 4 + w;
    float4 cc = pt4[cidx[c]];

    // neighbor 3x3x3 cell block (clamped)
    int cx = cellcoord(cc.x), cy = cellcoord(cc.y), cz = cellcoord(cc.z);
    int x0 = max(cx - 1, 0), x1 = min(cx + 1, GD - 1), lx = x1 - x0 + 1;
    int y0 = max(cy - 1, 0), y1 = min(cy + 1, GD - 1), ly = y1 - y0 + 1;
    int z0 = max(cz - 1, 0), z1 = min(cz + 1, GD - 1), lz = z1 - z0 + 1;
    int L = lx * ly * lz;

    int cellc = 0, cstart = 0;
    if (lane < L) {
        int lxy = lx * ly;
        int iz = lane / lxy, rem = lane - iz * lxy;
        int iy = rem / lx, ix = rem - iy * lx;
        int cell = ((z0 + iz) * GD + (y0 + iy)) * GD + (x0 + ix);
        cellc = cellCnt[cell];
        cstart = cellStart[cell];
    }
    // wave inclusive prefix over cell counts
    int pfx = cellc;
#pragma unroll
    for (int d = 1; d < 32; d <<= 1) {
        int o = __shfl_up(pfx, d);
        if (lane >= d) pfx += o;
    }
    if (lane == 0) scnt_s[w] = 0;
    int T = min(__shfl(pfx, L - 1), SPCAP);

    // build compact candidate-slot list: spbuf[e] = sorted-array index
    for (int j = 0; j < L; ++j) {
        int cj = __shfl(cellc, j);
        int ej = __shfl(pfx, j) - cj;
        int sj = __shfl(cstart, j);
        for (int i = lane; i < cj; i += 64) {
            int e2 = ej + i;
            if (e2 < SPCAP) spbuf[w][e2] = sj + i;
        }
    }

    // stream candidates: independent LDS read + global gather + test
    ull* key = keys[w];
    for (int base = 0; base < T; base += 64) {
        int s = base + lane;
        if (s < T) {
            int sp = spbuf[w][s];
            float4 p = sorted4[sp];
            int pid = sidx[sp];
            float dot = fmaf(p.z, cc.z, fmaf(p.y, cc.y, p.x * cc.x));
            float tt = fmaf(-2.f, dot, cc.w) + p.w;
            if (tt <= R2SAFE) {
                float d = sqrtf(fabsf(tt));
                if (d <= RADIUS_F) {
                    int slot = atomicAdd(&scnt_s[w], 1);
                    if (slot < CAPK)
                        key[slot] = (((ull)__float_as_uint(d)) << 32) | (unsigned)pid;
                }
            }
        }
    }

    // top-64 by (d_bits, idx) total order
    int n = min(scnt_s[w], CAPK);
    int nsel = min(n, 64);
    if (n > 64) {
        for (int i = lane; i < n; i += 64) {
            ull ki = key[i];
            int r = 0;
            for (int j = 0; j < n; ++j) r += (key[j] < ki) ? 1 : 0;
            if (r < 64) selb[w][r] = (int)(unsigned)(ki & 0xffffffffu);
        }
    } else {
        for (int i = lane; i < n; i += 64)
            selb[w][i] = (int)(unsigned)(key[i] & 0xffffffffu);
    }

    if (lane < nsel) selG[(size_t)c * 64 + lane] = selb[w][lane];
    if (lane == 0) nselG[c] = nsel;
}

// -------- K5: f16 MFMA MLP + masked max (weights straight from L2) -------
__global__ __launch_bounds__(256) void sa_mlp2_kernel(
    const float4* __restrict__ pt4, const int* __restrict__ cidx,
    const int* __restrict__ selG, const int* __restrict__ nselG,
    const _Float16* __restrict__ wf16,
    const float* __restrict__ b1, const float* __restrict__ b2,
    const float* __restrict__ b3, float* __restrict__ out) {

    __shared__ __align__(16) _Float16 featb[4][1024];  // [64 row][16 k]
    __shared__ __align__(16) _Float16 hbuf[4][4096];   // [64][64] swizzled

    int t = threadIdx.x, w = t >> 6, lane = t & 63;
    int c = blockIdx.x * 4 + w;
    int nsel = nselG[c];
    float4 cc = pt4[cidx[c]];

    // gather features -> f16 LDS [64][16] (K padded 6->16)
    {
        _Float16 z = (_Float16)0.f;
        f16x8 lo8 = {z, z, z, z, z, z, z, z};
        if (lane < nsel) {
            float4 p = pt4[selG[(size_t)c * 64 + lane]];
            lo8[0] = (_Float16)p.x; lo8[1] = (_Float16)p.y; lo8[2] = (_Float16)p.z;
            lo8[3] = (_Float16)(p.x - cc.x);
            lo8[4] = (_Float16)(p.y - cc.y);
            lo8[5] = (_Float16)(p.z - cc.z);
        }
        f16x8 hi8 = {z, z, z, z, z, z, z, z};
        *(f16x8*)&featb[w][lane * 16 + 0] = lo8;
        *(f16x8*)&featb[w][lane * 16 + 8] = hi8;
    }

    int r16 = lane & 15, g = lane >> 4;
    _Float16* h = hbuf[w];
    const _Float16* w1 = wf16;
    const _Float16* w2 = wf16 + 1024;
    const _Float16* w3 = wf16 + 5120;

    // ---- L1: feat[64x16(6)] @ W1 -> relu -> h swizzled ----
    {
        f16x4 a1[4];
#pragma unroll
        for (int m = 0; m < 4; ++m)
            a1[m] = *(const f16x4*)&featb[w][(m * 16 + r16) * 16 + g * 4];
#pragma unroll
        for (int nn = 0; nn < 4; ++nn) {
            int col = nn * 16 + r16;
            f16x4 b = *(const f16x4*)&w1[col * 16 + g * 4];
            float bb = b1[col];
#pragma unroll
            for (int m = 0; m < 4; ++m) {
                f32x4 acc = {bb, bb, bb, bb};
                acc = __builtin_amdgcn_mfma_f32_16x16x16f16(a1[m], b, acc, 0, 0, 0);
#pragma unroll
                for (int reg = 0; reg < 4; ++reg) {
                    int row = m * 16 + g * 4 + reg;
                    h[row * 64 + (col ^ ((row & 7) << 3))] =
                        (_Float16)fmaxf(acc[reg], 0.f);
                }
            }
        }
    }

    // ---- L2: h @ W2 -> relu -> h (A preloaded) ----
    {
        f16x8 a2[4][2];
#pragma unroll
        for (int m = 0; m < 4; ++m)
#pragma unroll
            for (int kt = 0; kt < 2; ++kt) {
                int row = m * 16 + r16;
                int k0 = kt * 32 + g * 8;
                a2[m][kt] = *(const f16x8*)&h[row * 64 + (k0 ^ ((row & 7) << 3))];
            }
#pragma unroll
        for (int nn = 0; nn < 4; ++nn) {
            int col = nn * 16 + r16;
            f16x8 bA = *(const f16x8*)&w2[col * 64 + g * 8];
            f16x8 bB = *(const f16x8*)&w2[col * 64 + 32 + g * 8];
            float bb = b2[col];
#pragma unroll
            for (int m = 0; m < 4; ++m) {
                f32x4 acc = {bb, bb, bb, bb};
                acc = __builtin_amdgcn_mfma_f32_16x16x32_f16(a2[m][0], bA, acc, 0, 0, 0);
                acc = __builtin_amdgcn_mfma_f32_16x16x32_f16(a2[m][1], bB, acc, 0, 0, 0);
#pragma unroll
                for (int reg = 0; reg < 4; ++reg) {
                    int row = m * 16 + g * 4 + reg;
                    h[row * 64 + (col ^ ((row & 7) << 3))] =
                        (_Float16)fmaxf(acc[reg], 0.f);
                }
            }
        }
    }

    // ---- L3: h @ W3 + mask + max over rows ----
    {
        f16x8 a3[4][2];
#pragma unroll
        for (int m = 0; m < 4; ++m)
#pragma unroll
            for (int kt = 0; kt < 2; ++kt) {
                int row = m * 16 + r16;
                int k0 = kt * 32 + g * 8;
                a3[m][kt] = *(const f16x8*)&h[row * 64 + (k0 ^ ((row & 7) << 3))];
            }
        float ninf = __int_as_float(0xff800000);
#pragma unroll
        for (int nn = 0; nn < 8; ++nn) {
            int col = nn * 16 + r16;
            f16x8 bA = *(const f16x8*)&w3[col * 64 + g * 8];
            f16x8 bB = *(const f16x8*)&w3[col * 64 + 32 + g * 8];
            float bb = b3[col];
            float vm = ninf;
#pragma unroll
            for (int m = 0; m < 4; ++m) {
                f32x4 acc = {bb, bb, bb, bb};
                acc = __builtin_amdgcn_mfma_f32_16x16x32_f16(a3[m][0], bA, acc, 0, 0, 0);
                acc = __builtin_amdgcn_mfma_f32_16x16x32_f16(a3[m][1], bB, acc, 0, 0, 0);
#pragma unroll
                for (int reg = 0; reg < 4; ++reg) {
                    int row = m * 16 + g * 4 + reg;
                    if (row < nsel) vm = fmaxf(vm, acc[reg]);
                }
            }
            vm = fmaxf(vm, __shfl_xor(vm, 16));
            vm = fmaxf(vm, __shfl_xor(vm, 32));
            if (lane < 16) out[(size_t)c * 128 + nn * 16 + lane] = vm;
        }
    }
}

extern "C" void kernel_launch(void* const* d_in, const int* in_sizes, int n_in,
                              void* d_out, int out_size, void* d_ws, size_t ws_size,
                              hipStream_t stream) {
    const float* vtx = (const float*)d_in[0];
    const int* cidx  = (const int*)d_in[1];
    const float* W1  = (const float*)d_in[2];
    const float* b1  = (const float*)d_in[3];
    const float* W2  = (const float*)d_in[4];
    const float* b2  = (const float*)d_in[5];
    const float* W3  = (const float*)d_in[6];
    const float* b3  = (const float*)d_in[7];
    float* out = (float*)d_out;

    int N = in_sizes[0] / 3;   // 65536
    int M = in_sizes[1];       // 4096

    char* ws = (char*)d_ws;
    size_t off = 0;
    float4* pt4     = (float4*)(ws + off); off += (size_t)N * 16;
    float4* sorted4 = (float4*)(ws + off); off += (size_t)N * 16;
    int* sidx       = (int*)(ws + off);    off += (size_t)N * 4;
    int* cid        = (int*)(ws + off);    off += (size_t)N * 4;
    int* cellCnt    = (int*)(ws + off);    off += (size_t)NC * 4;
    int* cursor     = (int*)(ws + off);    off += 16;
    int* cellStart  = (int*)(ws + off);    off += (size_t)NC * 4;
    int* cellCur    = (int*)(ws + off);    off += (size_t)NC * 4;
    int* selG       = (int*)(ws + off);    off += (size_t)M * 64 * 4;
    int* nselG      = (int*)(ws + off);    off += (size_t)M * 4;
    _Float16* wf16  = (_Float16*)(ws + off);

    hipMemsetAsync(cellCnt, 0, (size_t)NC * 4 + 16, stream);  // counts + cursor
    sa_prep_kernel<<<512, 256, 0, stream>>>(vtx, pt4, cid, cellCnt, N,
                                            W1, W2, W3, wf16);
    sa_offsets_kernel<<<(NC + 255) / 256, 256, 0, stream>>>(cellCnt, cellStart,
                                                            cellCur, cursor);
    sa_scatter_kernel<<<(N + 255) / 256, 256, 0, stream>>>(pt4, cid, cellCur,
                                                           sorted4, sidx, N);
    sa_collect_kernel<<<M / 4, 256, 0, stream>>>(pt4, cidx, sorted4, sidx,
                                                 cellCnt, cellStart, selG, nselG);
    sa_mlp2_kernel<<<M / 4, 256, 0, stream>>>(pt4, cidx, selG, nselG, wf16,
                                              b1, b2, b3, out);
}

// Round 6
// 86.439 us; speedup vs baseline: 1.0014x; 1.0014x over previous
//
#include <hip/hip_runtime.h>
#include <hip/hip_bf16.h>

#define GD     50          // grid cells per dim
#define NC     (GD*GD*GD)  // 125000
#define GORG   5.0f
#define GINV   5.0f        // 1/cellsize
#define CAPK   256         // in-radius candidate capacity per centroid
#define SPCAP  2048        // scanned-candidate capacity per centroid
#define RADIUS_F 0.2f
#define R2SAFE 0.0401f

typedef unsigned long long ull;
typedef __attribute__((ext_vector_type(4))) _Float16 f16x4;
typedef __attribute__((ext_vector_type(8))) _Float16 f16x8;
typedef __attribute__((ext_vector_type(4))) float    f32x4;

__device__ __forceinline__ int cellcoord(float v) {
    int c = (int)floorf((v + GORG) * GINV);
    return min(max(c, 0), GD - 1);
}

// -------- K0: zero cellCnt + cursor (runtime fillBuffer is 40us!) ---------
__global__ void sa_zero_kernel(int4* __restrict__ dst, int n4) {
    int i = blockIdx.x * blockDim.x + threadIdx.x;
    int stride = gridDim.x * blockDim.x;
    for (; i < n4; i += stride) dst[i] = make_int4(0, 0, 0, 0);
}

// -------- K1: pack pt4, cell ids, cell counts, f16 weights ----------------
__global__ void sa_prep_kernel(const float* __restrict__ vtx,
                               float4* __restrict__ pt4,
                               int* __restrict__ cid,
                               int* __restrict__ cellCnt,
                               int N,
                               const float* __restrict__ W1,
                               const float* __restrict__ W2,
                               const float* __restrict__ W3,
                               _Float16* __restrict__ wf16) {
    int i = blockIdx.x * blockDim.x + threadIdx.x;
    int stride = gridDim.x * blockDim.x;
    for (int p = i; p < N; p += stride) {
        float x = vtx[3 * p], y = vtx[3 * p + 1], z = vtx[3 * p + 2];
        float sn = fmaf(z, z, fmaf(y, y, x * x));
        pt4[p] = make_float4(x, y, z, sn);
        int cc = (cellcoord(z) * GD + cellcoord(y)) * GD + cellcoord(x);
        cid[p] = cc;
        atomicAdd(&cellCnt[cc], 1);
    }
    // W1t: [64 col][16 k], k>=6 zero (offset 0)
    for (int e = i; e < 1024; e += stride) {
        int col = e >> 4, k = e & 15;
        wf16[e] = (k < 6) ? (_Float16)W1[k * 64 + col] : (_Float16)0.f;
    }
    // W2t: [64 col][64 k] (offset 1024)
    for (int e = i; e < 4096; e += stride) {
        int col = e >> 6, k = e & 63;
        wf16[1024 + e] = (_Float16)W2[k * 64 + col];
    }
    // W3t: [128 col][64 k] (offset 5120)
    for (int e = i; e < 8192; e += stride) {
        int col = e >> 6, k = e & 63;
        wf16[5120 + e] = (_Float16)W3[k * 128 + col];
    }
}

// -------- K2: CSR offsets via block scan + one atomic base per block ------
__global__ __launch_bounds__(256) void sa_offsets_kernel(
    const int* __restrict__ cellCnt, int* __restrict__ cellStart,
    int* __restrict__ cellCur, int* __restrict__ cursor) {
    __shared__ int sc[256];
    __shared__ int base_s;
    int t = threadIdx.x;
    int i = blockIdx.x * 256 + t;
    int c = (i < NC) ? cellCnt[i] : 0;
    sc[t] = c;
    __syncthreads();
    for (int d = 1; d < 256; d <<= 1) {
        int o = (t >= d) ? sc[t - d] : 0;
        __syncthreads();
        sc[t] += o;
        __syncthreads();
    }
    if (t == 255) base_s = atomicAdd(cursor, sc[255]);
    __syncthreads();
    int start = base_s + sc[t] - c;
    if (i < NC) { cellStart[i] = start; cellCur[i] = start; }
}

// -------- K3: scatter points into cell-sorted order -----------------------
__global__ void sa_scatter_kernel(const float4* __restrict__ pt4,
                                  const int* __restrict__ cid,
                                  int* __restrict__ cellCur,
                                  float4* __restrict__ sorted4,
                                  int* __restrict__ sidx, int N) {
    int p = blockIdx.x * blockDim.x + threadIdx.x;
    if (p < N) {
        int pos = atomicAdd(&cellCur[cid[p]], 1);
        sorted4[pos] = pt4[p];
        sidx[pos] = p;
    }
}

// -------- K4: collect in-radius candidates + top-64 select ----------------
__global__ __launch_bounds__(256) void sa_collect_kernel(
    const float4* __restrict__ pt4, const int* __restrict__ cidx,
    const float4* __restrict__ sorted4, const int* __restrict__ sidx,
    const int* __restrict__ cellCnt, const int* __restrict__ cellStart,
    int* __restrict__ selG, int* __restrict__ nselG) {

    __shared__ int spbuf[4][SPCAP];      // 32 KB
    __shared__ ull  keys[4][CAPK];       // 8 KB
    __shared__ int  selb[4][64];
    __shared__ int  scnt_s[4];

    int t = threadIdx.x, w = t >> 6, lane = t & 63;
    int c = blockIdx.x * 4 + w;
    float4 cc = pt4[cidx[c]];

    // neighbor 3x3x3 cell block (clamped)
    int cx = cellcoord(cc.x), cy = cellcoord(cc.y), cz = cellcoord(cc.z);
    int x0 = max(cx - 1, 0), x1 = min(cx + 1, GD - 1), lx = x1 - x0 + 1;
    int y0 = max(cy - 1, 0), y1 = min(cy + 1, GD - 1), ly = y1 - y0 + 1;
    int z0 = max(cz - 1, 0), z1 = min(cz + 1, GD - 1), lz = z1 - z0 + 1;
    int L = lx * ly * lz;

    int cellc = 0, cstart = 0;
    if (lane < L) {
        int lxy = lx * ly;
        int iz = lane / lxy, rem = lane - iz * lxy;
        int iy = rem / lx, ix = rem - iy * lx;
        int cell = ((z0 + iz) * GD + (y0 + iy)) * GD + (x0 + ix);
        cellc = cellCnt[cell];
        cstart = cellStart[cell];
    }
    // wave inclusive prefix over cell counts
    int pfx = cellc;
#pragma unroll
    for (int d = 1; d < 32; d <<= 1) {
        int o = __shfl_up(pfx, d);
        if (lane >= d) pfx += o;
    }
    if (lane == 0) scnt_s[w] = 0;
    int T = min(__shfl(pfx, L - 1), SPCAP);

    // build compact candidate-slot list: spbuf[e] = sorted-array index
    for (int j = 0; j < L; ++j) {
        int cj = __shfl(cellc, j);
        int ej = __shfl(pfx, j) - cj;
        int sj = __shfl(cstart, j);
        for (int i = lane; i < cj; i += 64) {
            int e2 = ej + i;
            if (e2 < SPCAP) spbuf[w][e2] = sj + i;
        }
    }

    // stream candidates: independent LDS read + global gather + test
    ull* key = keys[w];
    for (int base = 0; base < T; base += 64) {
        int s = base + lane;
        if (s < T) {
            int sp = spbuf[w][s];
            float4 p = sorted4[sp];
            int pid = sidx[sp];
            float dot = fmaf(p.z, cc.z, fmaf(p.y, cc.y, p.x * cc.x));
            float tt = fmaf(-2.f, dot, cc.w) + p.w;
            if (tt <= R2SAFE) {
                float d = sqrtf(fabsf(tt));
                if (d <= RADIUS_F) {
                    int slot = atomicAdd(&scnt_s[w], 1);
                    if (slot < CAPK)
                        key[slot] = (((ull)__float_as_uint(d)) << 32) | (unsigned)pid;
                }
            }
        }
    }

    // top-64 by (d_bits, idx) total order
    int n = min(scnt_s[w], CAPK);
    int nsel = min(n, 64);
    if (n > 64) {
        for (int i = lane; i < n; i += 64) {
            ull ki = key[i];
            int r = 0;
            for (int j = 0; j < n; ++j) r += (key[j] < ki) ? 1 : 0;
            if (r < 64) selb[w][r] = (int)(unsigned)(ki & 0xffffffffu);
        }
    } else {
        for (int i = lane; i < n; i += 64)
            selb[w][i] = (int)(unsigned)(key[i] & 0xffffffffu);
    }

    if (lane < nsel) selG[(size_t)c * 64 + lane] = selb[w][lane];
    if (lane == 0) nselG[c] = nsel;
}

// -------- K5: f16 MFMA MLP + masked max (weights straight from L2) -------
__global__ __launch_bounds__(256) void sa_mlp2_kernel(
    const float4* __restrict__ pt4, const int* __restrict__ cidx,
    const int* __restrict__ selG, const int* __restrict__ nselG,
    const _Float16* __restrict__ wf16,
    const float* __restrict__ b1, const float* __restrict__ b2,
    const float* __restrict__ b3, float* __restrict__ out) {

    __shared__ __align__(16) _Float16 featb[4][1024];  // [64 row][16 k]
    __shared__ __align__(16) _Float16 hbuf[4][4096];   // [64][64] swizzled

    int t = threadIdx.x, w = t >> 6, lane = t & 63;
    int c = blockIdx.x * 4 + w;
    int nsel = nselG[c];
    float4 cc = pt4[cidx[c]];

    // gather features -> f16 LDS [64][16] (K padded 6->16)
    {
        _Float16 z = (_Float16)0.f;
        f16x8 lo8 = {z, z, z, z, z, z, z, z};
        if (lane < nsel) {
            float4 p = pt4[selG[(size_t)c * 64 + lane]];
            lo8[0] = (_Float16)p.x; lo8[1] = (_Float16)p.y; lo8[2] = (_Float16)p.z;
            lo8[3] = (_Float16)(p.x - cc.x);
            lo8[4] = (_Float16)(p.y - cc.y);
            lo8[5] = (_Float16)(p.z - cc.z);
        }
        f16x8 hi8 = {z, z, z, z, z, z, z, z};
        *(f16x8*)&featb[w][lane * 16 + 0] = lo8;
        *(f16x8*)&featb[w][lane * 16 + 8] = hi8;
    }

    int r16 = lane & 15, g = lane >> 4;
    _Float16* h = hbuf[w];
    const _Float16* w1 = wf16;
    const _Float16* w2 = wf16 + 1024;
    const _Float16* w3 = wf16 + 5120;

    // ---- L1: feat[64x16(6)] @ W1 -> relu -> h swizzled ----
    {
        f16x4 a1[4];
#pragma unroll
        for (int m = 0; m < 4; ++m)
            a1[m] = *(const f16x4*)&featb[w][(m * 16 + r16) * 16 + g * 4];
#pragma unroll
        for (int nn = 0; nn < 4; ++nn) {
            int col = nn * 16 + r16;
            f16x4 b = *(const f16x4*)&w1[col * 16 + g * 4];
            float bb = b1[col];
#pragma unroll
            for (int m = 0; m < 4; ++m) {
                f32x4 acc = {bb, bb, bb, bb};
                acc = __builtin_amdgcn_mfma_f32_16x16x16f16(a1[m], b, acc, 0, 0, 0);
#pragma unroll
                for (int reg = 0; reg < 4; ++reg) {
                    int row = m * 16 + g * 4 + reg;
                    h[row * 64 + (col ^ ((row & 7) << 3))] =
                        (_Float16)fmaxf(acc[reg], 0.f);
                }
            }
        }
    }

    // ---- L2: h @ W2 -> relu -> h (A preloaded) ----
    {
        f16x8 a2[4][2];
#pragma unroll
        for (int m = 0; m < 4; ++m)
#pragma unroll
            for (int kt = 0; kt < 2; ++kt) {
                int row = m * 16 + r16;
                int k0 = kt * 32 + g * 8;
                a2[m][kt] = *(const f16x8*)&h[row * 64 + (k0 ^ ((row & 7) << 3))];
            }
#pragma unroll
        for (int nn = 0; nn < 4; ++nn) {
            int col = nn * 16 + r16;
            f16x8 bA = *(const f16x8*)&w2[col * 64 + g * 8];
            f16x8 bB = *(const f16x8*)&w2[col * 64 + 32 + g * 8];
            float bb = b2[col];
#pragma unroll
            for (int m = 0; m < 4; ++m) {
                f32x4 acc = {bb, bb, bb, bb};
                acc = __builtin_amdgcn_mfma_f32_16x16x32_f16(a2[m][0], bA, acc, 0, 0, 0);
                acc = __builtin_amdgcn_mfma_f32_16x16x32_f16(a2[m][1], bB, acc, 0, 0, 0);
#pragma unroll
                for (int reg = 0; reg < 4; ++reg) {
                    int row = m * 16 + g * 4 + reg;
                    h[row * 64 + (col ^ ((row & 7) << 3))] =
                        (_Float16)fmaxf(acc[reg], 0.f);
                }
            }
        }
    }

    // ---- L3: h @ W3 + mask + max over rows ----
    {
        f16x8 a3[4][2];
#pragma unroll
        for (int m = 0; m < 4; ++m)
#pragma unroll
            for (int kt = 0; kt < 2; ++kt) {
                int row = m * 16 + r16;
                int k0 = kt * 32 + g * 8;
                a3[m][kt] = *(const f16x8*)&h[row * 64 + (k0 ^ ((row & 7) << 3))];
            }
        float ninf = __int_as_float(0xff800000);
#pragma unroll
        for (int nn = 0; nn < 8; ++nn) {
            int col = nn * 16 + r16;
            f16x8 bA = *(const f16x8*)&w3[col * 64 + g * 8];
            f16x8 bB = *(const f16x8*)&w3[col * 64 + 32 + g * 8];
            float bb = b3[col];
            float vm = ninf;
#pragma unroll
            for (int m = 0; m < 4; ++m) {
                f32x4 acc = {bb, bb, bb, bb};
                acc = __builtin_amdgcn_mfma_f32_16x16x32_f16(a3[m][0], bA, acc, 0, 0, 0);
                acc = __builtin_amdgcn_mfma_f32_16x16x32_f16(a3[m][1], bB, acc, 0, 0, 0);
#pragma unroll
                for (int reg = 0; reg < 4; ++reg) {
                    int row = m * 16 + g * 4 + reg;
                    if (row < nsel) vm = fmaxf(vm, acc[reg]);
                }
            }
            vm = fmaxf(vm, __shfl_xor(vm, 16));
            vm = fmaxf(vm, __shfl_xor(vm, 32));
            if (lane < 16) out[(size_t)c * 128 + nn * 16 + lane] = vm;
        }
    }
}

extern "C" void kernel_launch(void* const* d_in, const int* in_sizes, int n_in,
                              void* d_out, int out_size, void* d_ws, size_t ws_size,
                              hipStream_t stream) {
    const float* vtx = (const float*)d_in[0];
    const int* cidx  = (const int*)d_in[1];
    const float* W1  = (const float*)d_in[2];
    const float* b1  = (const float*)d_in[3];
    const float* W2  = (const float*)d_in[4];
    const float* b2  = (const float*)d_in[5];
    const float* W3  = (const float*)d_in[6];
    const float* b3  = (const float*)d_in[7];
    float* out = (float*)d_out;

    int N = in_sizes[0] / 3;   // 65536
    int M = in_sizes[1];       // 4096

    char* ws = (char*)d_ws;
    size_t off = 0;
    float4* pt4     = (float4*)(ws + off); off += (size_t)N * 16;
    float4* sorted4 = (float4*)(ws + off); off += (size_t)N * 16;
    int* sidx       = (int*)(ws + off);    off += (size_t)N * 4;
    int* cid        = (int*)(ws + off);    off += (size_t)N * 4;
    int* cellCnt    = (int*)(ws + off);    off += (size_t)NC * 4;
    int* cursor     = (int*)(ws + off);    off += 16;
    int* cellStart  = (int*)(ws + off);    off += (size_t)NC * 4;
    int* cellCur    = (int*)(ws + off);    off += (size_t)NC * 4;
    int* selG       = (int*)(ws + off);    off += (size_t)M * 64 * 4;
    int* nselG      = (int*)(ws + off);    off += (size_t)M * 4;
    _Float16* wf16  = (_Float16*)(ws + off);

    // zero cellCnt + cursor (contiguous): NC*4+16 bytes = 31251 int4s
    sa_zero_kernel<<<256, 256, 0, stream>>>((int4*)cellCnt, (NC * 4 + 16) / 16);
    sa_prep_kernel<<<512, 256, 0, stream>>>(vtx, pt4, cid, cellCnt, N,
                                            W1, W2, W3, wf16);
    sa_offsets_kernel<<<(NC + 255) / 256, 256, 0, stream>>>(cellCnt, cellStart,
                                                            cellCur, cursor);
    sa_scatter_kernel<<<(N + 255) / 256, 256, 0, stream>>>(pt4, cid, cellCur,
                                                           sorted4, sidx, N);
    sa_collect_kernel<<<M / 4, 256, 0, stream>>>(pt4, cidx, sorted4, sidx,
                                                 cellCnt, cellStart, selG, nselG);
    sa_mlp2_kernel<<<M / 4, 256, 0, stream>>>(pt4, cidx, selG, nselG, wf16,
                                              b1, b2, b3, out);
}

// Round 7
// 72.713 us; speedup vs baseline: 1.1904x; 1.1888x over previous
//
#include <hip/hip_runtime.h>
#include <hip/hip_bf16.h>

#define GD     50          // grid cells per dim
#define NC     (GD*GD*GD)  // 125000
#define CAPK   256         // in-radius candidate capacity per centroid
#define RADIUS_F 0.2f
#define R2SAFE 0.0401f

typedef unsigned long long ull;
typedef __attribute__((ext_vector_type(4))) _Float16 f16x4;
typedef __attribute__((ext_vector_type(8))) _Float16 f16x8;
typedef __attribute__((ext_vector_type(4))) float    f32x4;

__device__ __forceinline__ int cellcoord(float v) {
    int c = (int)floorf((v + 5.0f) * 5.0f);
    return min(max(c, 0), GD - 1);
}

// -------- K0: zero cellCnt + cursor ---------------------------------------
__global__ void sa_zero_kernel(int4* __restrict__ dst, int n4) {
    int i = blockIdx.x * blockDim.x + threadIdx.x;
    int stride = gridDim.x * blockDim.x;
    for (; i < n4; i += stride) dst[i] = make_int4(0, 0, 0, 0);
}

// -------- K1: pack pt4, cell ids, cell counts, f16 weights ----------------
__global__ void sa_prep_kernel(const float* __restrict__ vtx,
                               float4* __restrict__ pt4,
                               int* __restrict__ cid,
                               int* __restrict__ cellCnt,
                               int N,
                               const float* __restrict__ W1,
                               const float* __restrict__ W2,
                               const float* __restrict__ W3,
                               _Float16* __restrict__ wf16) {
    int i = blockIdx.x * blockDim.x + threadIdx.x;
    int stride = gridDim.x * blockDim.x;
    for (int p = i; p < N; p += stride) {
        float x = vtx[3 * p], y = vtx[3 * p + 1], z = vtx[3 * p + 2];
        float sn = fmaf(z, z, fmaf(y, y, x * x));
        pt4[p] = make_float4(x, y, z, sn);
        int cc = (cellcoord(z) * GD + cellcoord(y)) * GD + cellcoord(x);
        cid[p] = cc;
        atomicAdd(&cellCnt[cc], 1);
    }
    for (int e = i; e < 1024; e += stride) {       // W1t [64 col][16 k]
        int col = e >> 4, k = e & 15;
        wf16[e] = (k < 6) ? (_Float16)W1[k * 64 + col] : (_Float16)0.f;
    }
    for (int e = i; e < 4096; e += stride) {       // W2t [64 col][64 k]
        int col = e >> 6, k = e & 63;
        wf16[1024 + e] = (_Float16)W2[k * 64 + col];
    }
    for (int e = i; e < 8192; e += stride) {       // W3t [128 col][64 k]
        int col = e >> 6, k = e & 63;
        wf16[5120 + e] = (_Float16)W3[k * 128 + col];
    }
}

// -------- K2: CSR offsets via block scan + one atomic base per block ------
__global__ __launch_bounds__(256) void sa_offsets_kernel(
    const int* __restrict__ cellCnt, int* __restrict__ cellStart,
    int* __restrict__ cellCur, int* __restrict__ cursor) {
    __shared__ int sc[256];
    __shared__ int base_s;
    int t = threadIdx.x;
    int i = blockIdx.x * 256 + t;
    int c = (i < NC) ? cellCnt[i] : 0;
    sc[t] = c;
    __syncthreads();
    for (int d = 1; d < 256; d <<= 1) {
        int o = (t >= d) ? sc[t - d] : 0;
        __syncthreads();
        sc[t] += o;
        __syncthreads();
    }
    if (t == 255) base_s = atomicAdd(cursor, sc[255]);
    __syncthreads();
    int start = base_s + sc[t] - c;
    if (i < NC) { cellStart[i] = start; cellCur[i] = start; }
}

// -------- K3: scatter points into cell-sorted order -----------------------
__global__ void sa_scatter_kernel(const float4* __restrict__ pt4,
                                  const int* __restrict__ cid,
                                  int* __restrict__ cellCur,
                                  float4* __restrict__ sorted4,
                                  int* __restrict__ sidx, int N) {
    int p = blockIdx.x * blockDim.x + threadIdx.x;
    if (p < N) {
        int pos = atomicAdd(&cellCur[cid[p]], 1);
        sorted4[pos] = pt4[p];
        sidx[pos] = p;
    }
}

// -------- K4: collect in-radius + top-64 + emit dense f16 features --------
__global__ __launch_bounds__(256) void sa_collect_kernel(
    const float4* __restrict__ pt4, const int* __restrict__ cidx,
    const float4* __restrict__ sorted4, const int* __restrict__ sidx,
    const int* __restrict__ cellCnt, const int* __restrict__ cellStart,
    _Float16* __restrict__ featG, int* __restrict__ nselG) {

    __shared__ ull keys[4][CAPK];   // 8 KB
    __shared__ int selb[4][64];     // 1 KB
    __shared__ int scnt_s[4];

    int t = threadIdx.x, w = t >> 6, lane = t & 63;
    int c = blockIdx.x * 4 + w;
    float4 cc = pt4[cidx[c]];

    // neighbor 3x3x3 cell block (clamped), AABB-pruned, in registers
    int cx = cellcoord(cc.x), cy = cellcoord(cc.y), cz = cellcoord(cc.z);
    int x0 = max(cx - 1, 0), x1 = min(cx + 1, GD - 1), lx = x1 - x0 + 1;
    int y0 = max(cy - 1, 0), y1 = min(cy + 1, GD - 1), ly = y1 - y0 + 1;
    int z0 = max(cz - 1, 0), z1 = min(cz + 1, GD - 1), lz = z1 - z0 + 1;
    int L = lx * ly * lz;

    int cellc = 0, cstart = 0;
    if (lane < L) {
        int lxy = lx * ly;
        int iz = lane / lxy, rem = lane - iz * lxy;
        int iy = rem / lx, ix = rem - iy * lx;
        int gx = x0 + ix, gy = y0 + iy, gz = z0 + iz;
        // closest point of cell AABB to centroid (edge cells open to inf)
        float xlo = (gx == 0) ? -1e30f : gx * 0.2f - 5.0f;
        float xhi = (gx == GD - 1) ? 1e30f : (gx + 1) * 0.2f - 5.0f;
        float ylo = (gy == 0) ? -1e30f : gy * 0.2f - 5.0f;
        float yhi = (gy == GD - 1) ? 1e30f : (gy + 1) * 0.2f - 5.0f;
        float zlo = (gz == 0) ? -1e30f : gz * 0.2f - 5.0f;
        float zhi = (gz == GD - 1) ? 1e30f : (gz + 1) * 0.2f - 5.0f;
        float dx = fmaxf(0.f, fmaxf(xlo - cc.x, cc.x - xhi));
        float dy = fmaxf(0.f, fmaxf(ylo - cc.y, cc.y - yhi));
        float dz = fmaxf(0.f, fmaxf(zlo - cc.z, cc.z - zhi));
        if (fmaf(dz, dz, fmaf(dy, dy, dx * dx)) <= R2SAFE) {
            int cell = (gz * GD + gy) * GD + gx;
            cellc = cellCnt[cell];
            cstart = cellStart[cell];
        }
    }
    // inclusive prefix over cell counts (wave)
    int pfx = cellc;
#pragma unroll
    for (int d = 1; d < 32; d <<= 1) {
        int o = __shfl_up(pfx, d);
        if (lane >= d) pfx += o;
    }
    int excl = pfx - cellc;           // exclusive prefix, lane j = cell j
    if (lane == 0) scnt_s[w] = 0;
    int T = __shfl(pfx, L - 1);

    // stream candidates: 5-step shfl binary search (no LDS) -> gather -> test
    ull* key = keys[w];
    for (int base = 0; base < T; base += 64) {
        int s = base + lane;
        int lo = 0, hi = L - 1;
#pragma unroll 5
        for (int it = 0; it < 5; ++it) {
            int mid = (lo + hi + 1) >> 1;
            int em = __shfl(excl, mid);
            if (lo < hi) { if (em <= s) lo = mid; else hi = mid - 1; }
        }
        int sp = __shfl(cstart, lo) + (s - __shfl(excl, lo));
        if (s < T) {
            float4 p = sorted4[sp];
            float dot = fmaf(p.z, cc.z, fmaf(p.y, cc.y, p.x * cc.x));
            float tt = fmaf(-2.f, dot, cc.w) + p.w;
            if (tt <= R2SAFE) {
                float d = sqrtf(fabsf(tt));
                if (d <= RADIUS_F) {
                    int pid = sidx[sp];
                    int slot = atomicAdd(&scnt_s[w], 1);
                    if (slot < CAPK)
                        key[slot] = (((ull)__float_as_uint(d)) << 32) | (unsigned)pid;
                }
            }
        }
    }

    // top-64 by (d_bits, idx) total order
    int n = min(scnt_s[w], CAPK);
    int nsel = min(n, 64);
    if (n > 64) {
        for (int i = lane; i < n; i += 64) {
            ull ki = key[i];
            int r = 0;
            for (int j = 0; j < n; ++j) r += (key[j] < ki) ? 1 : 0;
            if (r < 64) selb[w][r] = (int)(unsigned)(ki & 0xffffffffu);
        }
    } else {
        for (int i = lane; i < n; i += 64)
            selb[w][i] = (int)(unsigned)(key[i] & 0xffffffffu);
    }

    // emit dense f16 feature rows [64][16], zero-padded
    {
        _Float16 z = (_Float16)0.f;
        f16x8 lo8 = {z, z, z, z, z, z, z, z};
        if (lane < nsel) {
            float4 p = pt4[selb[w][lane]];
            lo8[0] = (_Float16)p.x; lo8[1] = (_Float16)p.y; lo8[2] = (_Float16)p.z;
            lo8[3] = (_Float16)(p.x - cc.x);
            lo8[4] = (_Float16)(p.y - cc.y);
            lo8[5] = (_Float16)(p.z - cc.z);
        }
        f16x8 hi8 = {z, z, z, z, z, z, z, z};
        _Float16* fr = featG + (size_t)c * 1024 + lane * 16;
        *(f16x8*)(fr + 0) = lo8;
        *(f16x8*)(fr + 8) = hi8;
    }
    if (lane == 0) nselG[c] = nsel;
}

// -------- K5: f16 MFMA MLP + masked max (feat + weights from L2) ----------
__global__ __launch_bounds__(256) void sa_mlp2_kernel(
    const _Float16* __restrict__ featG, const int* __restrict__ nselG,
    const _Float16* __restrict__ wf16,
    const float* __restrict__ b1, const float* __restrict__ b2,
    const float* __restrict__ b3, float* __restrict__ out) {

    __shared__ __align__(16) _Float16 hbuf[4][4096];   // [64][64] swizzled, 32 KB

    int t = threadIdx.x, w = t >> 6, lane = t & 63;
    int c = blockIdx.x * 4 + w;
    int nsel = nselG[c];

    int r16 = lane & 15, g = lane >> 4;
    _Float16* h = hbuf[w];
    const _Float16* fG = featG + (size_t)c * 1024;
    const _Float16* w1 = wf16;
    const _Float16* w2 = wf16 + 1024;
    const _Float16* w3 = wf16 + 5120;

    // ---- L1: feat[64x16(6)] @ W1 -> relu -> h swizzled ----
    {
        f16x4 a1[4];
#pragma unroll
        for (int m = 0; m < 4; ++m)
            a1[m] = *(const f16x4*)&fG[(m * 16 + r16) * 16 + g * 4];
#pragma unroll
        for (int nn = 0; nn < 4; ++nn) {
            int col = nn * 16 + r16;
            f16x4 b = *(const f16x4*)&w1[col * 16 + g * 4];
            float bb = b1[col];
#pragma unroll
            for (int m = 0; m < 4; ++m) {
                f32x4 acc = {bb, bb, bb, bb};
                acc = __builtin_amdgcn_mfma_f32_16x16x16f16(a1[m], b, acc, 0, 0, 0);
#pragma unroll
                for (int reg = 0; reg < 4; ++reg) {
                    int row = m * 16 + g * 4 + reg;
                    h[row * 64 + (col ^ ((row & 7) << 3))] =
                        (_Float16)fmaxf(acc[reg], 0.f);
                }
            }
        }
    }

    // ---- L2: h @ W2 -> relu -> h (A preloaded) ----
    {
        f16x8 a2[4][2];
#pragma unroll
        for (int m = 0; m < 4; ++m)
#pragma unroll
            for (int kt = 0; kt < 2; ++kt) {
                int row = m * 16 + r16;
                int k0 = kt * 32 + g * 8;
                a2[m][kt] = *(const f16x8*)&h[row * 64 + (k0 ^ ((row & 7) << 3))];
            }
#pragma unroll
        for (int nn = 0; nn < 4; ++nn) {
            int col = nn * 16 + r16;
            f16x8 bA = *(const f16x8*)&w2[col * 64 + g * 8];
            f16x8 bB = *(const f16x8*)&w2[col * 64 + 32 + g * 8];
            float bb = b2[col];
#pragma unroll
            for (int m = 0; m < 4; ++m) {
                f32x4 acc = {bb, bb, bb, bb};
                acc = __builtin_amdgcn_mfma_f32_16x16x32_f16(a2[m][0], bA, acc, 0, 0, 0);
                acc = __builtin_amdgcn_mfma_f32_16x16x32_f16(a2[m][1], bB, acc, 0, 0, 0);
#pragma unroll
                for (int reg = 0; reg < 4; ++reg) {
                    int row = m * 16 + g * 4 + reg;
                    h[row * 64 + (col ^ ((row & 7) << 3))] =
                        (_Float16)fmaxf(acc[reg], 0.f);
                }
            }
        }
    }

    // ---- L3: h @ W3 + mask + max over rows ----
    {
        f16x8 a3[4][2];
#pragma unroll
        for (int m = 0; m < 4; ++m)
#pragma unroll
            for (int kt = 0; kt < 2; ++kt) {
                int row = m * 16 + r16;
                int k0 = kt * 32 + g * 8;
                a3[m][kt] = *(const f16x8*)&h[row * 64 + (k0 ^ ((row & 7) << 3))];
            }
        float ninf = __int_as_float(0xff800000);
#pragma unroll
        for (int nn = 0; nn < 8; ++nn) {
            int col = nn * 16 + r16;
            f16x8 bA = *(const f16x8*)&w3[col * 64 + g * 8];
            f16x8 bB = *(const f16x8*)&w3[col * 64 + 32 + g * 8];
            float bb = b3[col];
            float vm = ninf;
#pragma unroll
            for (int m = 0; m < 4; ++m) {
                f32x4 acc = {bb, bb, bb, bb};
                acc = __builtin_amdgcn_mfma_f32_16x16x32_f16(a3[m][0], bA, acc, 0, 0, 0);
                acc = __builtin_amdgcn_mfma_f32_16x16x32_f16(a3[m][1], bB, acc, 0, 0, 0);
#pragma unroll
                for (int reg = 0; reg < 4; ++reg) {
                    int row = m * 16 + g * 4 + reg;
                    if (row < nsel) vm = fmaxf(vm, acc[reg]);
                }
            }
            vm = fmaxf(vm, __shfl_xor(vm, 16));
            vm = fmaxf(vm, __shfl_xor(vm, 32));
            if (lane < 16) out[(size_t)c * 128 + nn * 16 + lane] = vm;
        }
    }
}

extern "C" void kernel_launch(void* const* d_in, const int* in_sizes, int n_in,
                              void* d_out, int out_size, void* d_ws, size_t ws_size,
                              hipStream_t stream) {
    const float* vtx = (const float*)d_in[0];
    const int* cidx  = (const int*)d_in[1];
    const float* W1  = (const float*)d_in[2];
    const float* b1  = (const float*)d_in[3];
    const float* W2  = (const float*)d_in[4];
    const float* b2  = (const float*)d_in[5];
    const float* W3  = (const float*)d_in[6];
    const float* b3  = (const float*)d_in[7];
    float* out = (float*)d_out;

    int N = in_sizes[0] / 3;   // 65536
    int M = in_sizes[1];       // 4096

    char* ws = (char*)d_ws;
    size_t off = 0;
    float4* pt4     = (float4*)(ws + off); off += (size_t)N * 16;
    float4* sorted4 = (float4*)(ws + off); off += (size_t)N * 16;
    int* sidx       = (int*)(ws + off);    off += (size_t)N * 4;
    int* cid        = (int*)(ws + off);    off += (size_t)N * 4;
    int* cellCnt    = (int*)(ws + off);    off += (size_t)NC * 4;
    int* cursor     = (int*)(ws + off);    off += 16;
    int* cellStart  = (int*)(ws + off);    off += (size_t)NC * 4;
    int* cellCur    = (int*)(ws + off);    off += (size_t)NC * 4;
    _Float16* featG = (_Float16*)(ws + off); off += (size_t)M * 1024 * 2;
    int* nselG      = (int*)(ws + off);    off += (size_t)M * 4;
    _Float16* wf16  = (_Float16*)(ws + off);

    sa_zero_kernel<<<256, 256, 0, stream>>>((int4*)cellCnt, (NC * 4 + 16) / 16);
    sa_prep_kernel<<<512, 256, 0, stream>>>(vtx, pt4, cid, cellCnt, N,
                                            W1, W2, W3, wf16);
    sa_offsets_kernel<<<(NC + 255) / 256, 256, 0, stream>>>(cellCnt, cellStart,
                                                            cellCur, cursor);
    sa_scatter_kernel<<<(N + 255) / 256, 256, 0, stream>>>(pt4, cid, cellCur,
                                                           sorted4, sidx, N);
    sa_collect_kernel<<<M / 4, 256, 0, stream>>>(pt4, cidx, sorted4, sidx,
                                                 cellCnt, cellStart, featG, nselG);
    sa_mlp2_kernel<<<M / 4, 256, 0, stream>>>(featG, nselG, wf16,
                                              b1, b2, b3, out);
}